// Round 1
// baseline (1360.684 us; speedup 1.0000x reference)
//
#include <hip/hip_runtime.h>
#include <hip/hip_bf16.h>
#include <cstdint>
#include <cstddef>

#define B_ 2048
#define C_ 64
#define D_ 1024
#define E_ 128
#define NP 1152  // 1025 padded to 9*128

// output regions (f32 elements)
#define OFF_CE 131072ull                 // c_emb [B,C,E]
#define OFF_MU (131072ull + 16777216ull) // mu
#define OFF_LV (131072ull + 33554432ull) // logvar

using bf16x8 = __attribute__((ext_vector_type(8))) __bf16;
using s16x8  = __attribute__((ext_vector_type(8))) short;
using f32x4  = __attribute__((ext_vector_type(4))) float;

__device__ __forceinline__ unsigned short f2bf(float x) {
  unsigned u = __builtin_bit_cast(unsigned, x);
  return (unsigned short)((u + 0x7FFFu + ((u >> 16) & 1u)) >> 16);
}
__device__ __forceinline__ float bf2f(unsigned short h) {
  unsigned u = ((unsigned)h) << 16;
  return __builtin_bit_cast(float, u);
}
__device__ __forceinline__ void async16(const void* g, void* l) {
  __builtin_amdgcn_global_load_lds(
      (const __attribute__((address_space(1))) void*)g,
      (__attribute__((address_space(3))) void*)l, 16, 0, 0);
}

// ---------------- converters ----------------

__global__ __launch_bounds__(256) void convert_x_k(const float* __restrict__ x,
                                                   unsigned short* __restrict__ xb) {
  int idx = blockIdx.x * 256 + threadIdx.x;  // B*D/8 = 262144 threads
  const float4* xv = (const float4*)x;
  float4 a = xv[idx * 2], b = xv[idx * 2 + 1];
  unsigned w0 = f2bf(a.x) | ((unsigned)f2bf(a.y) << 16);
  unsigned w1 = f2bf(a.z) | ((unsigned)f2bf(a.w) << 16);
  unsigned w2 = f2bf(b.x) | ((unsigned)f2bf(b.y) << 16);
  unsigned w3 = f2bf(b.z) | ((unsigned)f2bf(b.w) << 16);
  ((uint4*)xb)[idx] = make_uint4(w0, w1, w2, w3);
}

// W1 [C,1024,1024] f32 (k-contraction-major rows) -> W1T [C,1024(n),1024(k)] bf16
__global__ void transpose_w1_k(const float* __restrict__ src0, unsigned short* __restrict__ dst0) {
  __shared__ float t[32][33];
  const int c = blockIdx.z;
  const int k0 = blockIdx.x << 5, n0 = blockIdx.y << 5;
  const int tx = threadIdx.x, ty = threadIdx.y;
  const float* src = src0 + ((size_t)c << 20);
#pragma unroll
  for (int r = 0; r < 4; ++r)
    t[ty + (r << 3)][tx] = src[((size_t)(k0 + ty + (r << 3)) << 10) + n0 + tx];
  __syncthreads();
  unsigned short* dst = dst0 + ((size_t)c << 20);
#pragma unroll
  for (int r = 0; r < 4; ++r)
    dst[((size_t)(n0 + ty + (r << 3)) << 10) + k0 + tx] = f2bf(t[tx][ty + (r << 3)]);
}

// Wl [C,1025,1025] f32 -> WlT [C,1152(n),1024(k)] bf16 (row k=1024 excluded, pad n with 0)
__global__ void transpose_wl_k(const float* __restrict__ Wl, unsigned short* __restrict__ WlT) {
  __shared__ float t[32][33];
  const int c = blockIdx.z;
  const int k0 = blockIdx.x << 5, n0 = blockIdx.y << 5;
  const int tx = threadIdx.x, ty = threadIdx.y;
  const float* src = Wl + (size_t)c * 1025 * 1025;
#pragma unroll
  for (int r = 0; r < 4; ++r) {
    int k = k0 + ty + (r << 3);
    int n = n0 + tx;
    t[ty + (r << 3)][tx] = (n < 1025) ? src[(size_t)k * 1025 + n] : 0.f;
  }
  __syncthreads();
  unsigned short* dst = WlT + (size_t)c * NP * 1024;
#pragma unroll
  for (int r = 0; r < 4; ++r)
    dst[(size_t)(n0 + ty + (r << 3)) * 1024 + k0 + tx] = f2bf(t[tx][ty + (r << 3)]);
}

// wlast (Wl row k=1024) and padded bl, both f32 [C,1152]
__global__ __launch_bounds__(256) void wlast_blp_k(const float* __restrict__ Wl,
                                                   const float* __restrict__ bl,
                                                   float* __restrict__ wlastf,
                                                   float* __restrict__ blpf) {
  int idx = blockIdx.x * 256 + threadIdx.x;  // C*NP = 73728
  int c = idx / NP, n = idx - c * NP;
  wlastf[idx] = (n < 1025) ? Wl[((size_t)c * 1025 + 1024) * 1025 + n] : 0.f;
  blpf[idx]   = (n < 1025) ? bl[(size_t)c * 1025 + n] : 0.f;
}

// [Wmu|Wlv] [1025,128] -> WheadT [256(n),1152(k)] bf16, zero-padded k
__global__ __launch_bounds__(256) void convert_whead_k(const float* __restrict__ Wmu,
                                                       const float* __restrict__ Wlv,
                                                       unsigned short* __restrict__ WheadT) {
  int idx = blockIdx.x * 256 + threadIdx.x;  // 256*NP = 294912
  int rr = idx / NP, k = idx - rr * NP;
  float v = 0.f;
  if (k < 1025) v = (rr < 128) ? Wmu[(size_t)k * 128 + rr] : Wlv[(size_t)k * 128 + (rr - 128)];
  WheadT[idx] = f2bf(v);
}

// ---------------- scorer: s = h . w2, c_pred = sigmoid(s + b2) ----------------

__global__ __launch_bounds__(256) void scorer_k(const unsigned short* __restrict__ h,
                                                const float* __restrict__ w2,
                                                const float* __restrict__ b2,
                                                float* __restrict__ pred_out,
                                                float* __restrict__ cpf) {
  int wv = (blockIdx.x << 2) + (threadIdx.x >> 6);  // row id = c*B + b
  int lane = threadIdx.x & 63;
  int c = wv >> 11, b = wv & 2047;
  const unsigned short* hr = h + ((size_t)wv << 10);
  const float* wr = w2 + (c << 10);
  float s = 0.f;
#pragma unroll
  for (int ch = 0; ch < 2; ++ch) {
    int base = ch * 512 + lane * 8;
    s16x8 hv = *(const s16x8*)(hr + base);
    float4 w0 = *(const float4*)(wr + base);
    float4 w1 = *(const float4*)(wr + base + 4);
    s += bf2f((unsigned short)hv[0]) * w0.x + bf2f((unsigned short)hv[1]) * w0.y +
         bf2f((unsigned short)hv[2]) * w0.z + bf2f((unsigned short)hv[3]) * w0.w +
         bf2f((unsigned short)hv[4]) * w1.x + bf2f((unsigned short)hv[5]) * w1.y +
         bf2f((unsigned short)hv[6]) * w1.z + bf2f((unsigned short)hv[7]) * w1.w;
  }
#pragma unroll
  for (int off = 32; off; off >>= 1) s += __shfl_xor(s, off);
  if (lane == 0) {
    float p = 1.f / (1.f + expf(-(s + b2[c])));
    pred_out[((size_t)b << 6) + c] = p;
    cpf[((size_t)b << 6) + c] = p;
  }
}

// ---------------- templated 128x128 MFMA GEMM (m97 structure) ----------------
// A [M,K] bf16 row-major, BT [N,K] bf16 row-major (k-contiguous). BK=32.
// MODE 0: h = relu(acc + b1[c,n])            -> obf [C][B][1024]
// MODE 1: emb = relu(acc + cp*wlast + blp)   -> obf [C][B][1152]
// MODE 2: mu/lv = acc + bias                 -> ofl (d_out)

template <int MODE>
__global__ __launch_bounds__(256) void gemm_k(const unsigned short* __restrict__ A,
                                              const unsigned short* __restrict__ BT,
                                              const int K,
                                              const float* __restrict__ e0,
                                              const float* __restrict__ e1,
                                              const float* __restrict__ e2,
                                              unsigned short* __restrict__ obf,
                                              float* __restrict__ ofl) {
  __shared__ unsigned short As[128 * 32];
  __shared__ unsigned short Bs[128 * 32];
  const int tid = threadIdx.x;
  const int lane = tid & 63;
  const int wid = tid >> 6;
  const int wr = wid >> 1, wc = wid & 1;
  const int l15 = lane & 15, l4 = lane >> 4;
  const int c = blockIdx.z;
  const int n0 = blockIdx.x << 7;
  const int m0 = blockIdx.y << 7;

  const unsigned short* Ab = A;
  const unsigned short* Bb;
  if constexpr (MODE == 0)      Bb = BT + ((size_t)c << 20);
  else if constexpr (MODE == 1) Bb = BT + (size_t)c * (NP * 1024);
  else                          Bb = BT;

  f32x4 acc[4][4];
#pragma unroll
  for (int i = 0; i < 4; ++i)
#pragma unroll
    for (int j = 0; j < 4; ++j) acc[i][j] = (f32x4)(0.f);

  const int rA = lane >> 2;         // row within 16-row group
  const int kA = (lane & 3) << 3;   // k element offset (0,8,16,24)
  const int j0 = wid << 1;

  for (int k0 = 0; k0 < K; k0 += 32) {
#pragma unroll
    for (int t = 0; t < 2; ++t) {
      const int j = j0 + t;
      async16(Ab + (size_t)(m0 + j * 16 + rA) * K + k0 + kA, (char*)As + (j << 10));
      async16(Bb + (size_t)(n0 + j * 16 + rA) * K + k0 + kA, (char*)Bs + (j << 10));
    }
    __syncthreads();
    bf16x8 av[4], bv[4];
#pragma unroll
    for (int i = 0; i < 4; ++i) {
      av[i] = *(const bf16x8*)(As + (((wr << 6) + (i << 4) + l15) << 5) + (l4 << 3));
      bv[i] = *(const bf16x8*)(Bs + (((wc << 6) + (i << 4) + l15) << 5) + (l4 << 3));
    }
#pragma unroll
    for (int i = 0; i < 4; ++i)
#pragma unroll
      for (int j = 0; j < 4; ++j)
        acc[i][j] = __builtin_amdgcn_mfma_f32_16x16x32_bf16(av[i], bv[j], acc[i][j], 0, 0, 0);
    __syncthreads();
  }

  int colL[4];
#pragma unroll
  for (int j = 0; j < 4; ++j) colL[j] = n0 + (wc << 6) + (j << 4) + l15;

  if constexpr (MODE == 0) {
    float bias[4];
#pragma unroll
    for (int j = 0; j < 4; ++j) bias[j] = e0[(c << 10) + colL[j]];
#pragma unroll
    for (int i = 0; i < 4; ++i)
#pragma unroll
      for (int r = 0; r < 4; ++r) {
        const int row = m0 + (wr << 6) + (i << 4) + (l4 << 2) + r;
        unsigned short* orow = obf + ((size_t)((c << 11) + row) << 10);
#pragma unroll
        for (int j = 0; j < 4; ++j) {
          float v = acc[i][j][r] + bias[j];
          orow[colL[j]] = f2bf(fmaxf(v, 0.f));
        }
      }
  } else if constexpr (MODE == 1) {
    float wl4[4], bb4[4];
#pragma unroll
    for (int j = 0; j < 4; ++j) {
      wl4[j] = e0[c * NP + colL[j]];
      bb4[j] = e1[c * NP + colL[j]];
    }
#pragma unroll
    for (int i = 0; i < 4; ++i)
#pragma unroll
      for (int r = 0; r < 4; ++r) {
        const int row = m0 + (wr << 6) + (i << 4) + (l4 << 2) + r;  // = b
        const float cp = e2[((size_t)row << 6) + c];
        unsigned short* orow = obf + (size_t)((c << 11) + row) * NP;
#pragma unroll
        for (int j = 0; j < 4; ++j) {
          float v = acc[i][j][r] + cp * wl4[j] + bb4[j];
          orow[colL[j]] = f2bf(fmaxf(v, 0.f));
        }
      }
  } else {
    float bias[4];
#pragma unroll
    for (int j = 0; j < 4; ++j) {
      int n = colL[j];
      bias[j] = (n < 128) ? e0[n] : e1[n - 128];
    }
#pragma unroll
    for (int i = 0; i < 4; ++i)
#pragma unroll
      for (int r = 0; r < 4; ++r) {
        const int rid = m0 + (wr << 6) + (i << 4) + (l4 << 2) + r;  // c*B + b
        const int cc = rid >> 11, b = rid & 2047;
        const size_t ib = (((size_t)b << 6) + cc) << 7;
#pragma unroll
        for (int j = 0; j < 4; ++j) {
          float v = acc[i][j][r] + bias[j];
          int n = colL[j];
          if (n < 128) {
            ofl[OFF_MU + ib + n] = v;
            ofl[OFF_CE + ib + n] = v;
          } else {
            ofl[OFF_LV + ib + (n - 128)] = v;
          }
        }
      }
  }
}

// ---------------- launcher ----------------

extern "C" void kernel_launch(void* const* d_in, const int* in_sizes, int n_in,
                              void* d_out, int out_size, void* d_ws, size_t ws_size,
                              hipStream_t stream) {
  const float* x   = (const float*)d_in[0];
  const float* W1  = (const float*)d_in[2];
  const float* b1  = (const float*)d_in[3];
  const float* w2  = (const float*)d_in[4];
  const float* b2  = (const float*)d_in[5];
  const float* Wl  = (const float*)d_in[6];
  const float* bl  = (const float*)d_in[7];
  const float* Wmu = (const float*)d_in[8];
  const float* bmu = (const float*)d_in[9];
  const float* Wlv = (const float*)d_in[10];
  const float* blv = (const float*)d_in[11];
  float* out = (float*)d_out;

  char* ws = (char*)d_ws;
  unsigned short* xb     = (unsigned short*)(ws);                  //   4,194,304
  unsigned short* WT     = (unsigned short*)(ws + 4194304ull);     // 150,994,944 (W1T, later WlT)
  float* wlastf          = (float*)(ws + 155189248ull);            //     294,912
  float* blpf            = (float*)(ws + 155484160ull);            //     294,912
  unsigned short* WheadT = (unsigned short*)(ws + 155779072ull);   //     589,824
  float* cpf             = (float*)(ws + 156368896ull);            //     524,288
  unsigned short* hemb   = (unsigned short*)(ws + 156893184ull);   // 301,989,888 (h, later emb)
  // total: 458,883,072 bytes

  convert_x_k<<<1024, 256, 0, stream>>>(x, xb);
  transpose_w1_k<<<dim3(32, 32, 64), dim3(32, 8), 0, stream>>>(W1, WT);
  gemm_k<0><<<dim3(8, 16, 64), 256, 0, stream>>>(xb, WT, 1024, b1, nullptr, nullptr, hemb, nullptr);
  scorer_k<<<32768, 256, 0, stream>>>(hemb, w2, b2, out, cpf);
  transpose_wl_k<<<dim3(32, 36, 64), dim3(32, 8), 0, stream>>>(Wl, WT);
  wlast_blp_k<<<288, 256, 0, stream>>>(Wl, bl, wlastf, blpf);
  convert_whead_k<<<1152, 256, 0, stream>>>(Wmu, Wlv, WheadT);
  gemm_k<1><<<dim3(9, 16, 64), 256, 0, stream>>>(xb, WT, 1024, wlastf, blpf, cpf, hemb, nullptr);
  gemm_k<2><<<dim3(2, 1024, 1), 256, 0, stream>>>(hemb, WheadT, 1152, bmu, blv, nullptr, nullptr, out);
}

// Round 2
// 1038.436 us; speedup vs baseline: 1.3103x; 1.3103x over previous
//
#include <hip/hip_runtime.h>
#include <hip/hip_bf16.h>
#include <cstdint>
#include <cstddef>

#define NP 1152  // 1025 padded to 9*128

// output regions (f32 elements)
#define OFF_CE 131072ull                 // c_emb [B,C,E]
#define OFF_MU (131072ull + 16777216ull) // mu
#define OFF_LV (131072ull + 33554432ull) // logvar

using bf16x8 = __attribute__((ext_vector_type(8))) __bf16;
using s16x8  = __attribute__((ext_vector_type(8))) short;
using f32x4  = __attribute__((ext_vector_type(4))) float;

__device__ __forceinline__ unsigned short f2bf(float x) {
  unsigned u = __builtin_bit_cast(unsigned, x);
  return (unsigned short)((u + 0x7FFFu + ((u >> 16) & 1u)) >> 16);
}
__device__ __forceinline__ float bf2f(unsigned short h) {
  unsigned u = ((unsigned)h) << 16;
  return __builtin_bit_cast(float, u);
}
__device__ __forceinline__ void async16(const void* g, void* l) {
  __builtin_amdgcn_global_load_lds(
      (const __attribute__((address_space(1))) void*)g,
      (__attribute__((address_space(3))) void*)l, 16, 0, 0);
}

// ---------------- converters (unchanged from round 1) ----------------

__global__ __launch_bounds__(256) void convert_x_k(const float* __restrict__ x,
                                                   unsigned short* __restrict__ xb) {
  int idx = blockIdx.x * 256 + threadIdx.x;
  const float4* xv = (const float4*)x;
  float4 a = xv[idx * 2], b = xv[idx * 2 + 1];
  unsigned w0 = f2bf(a.x) | ((unsigned)f2bf(a.y) << 16);
  unsigned w1 = f2bf(a.z) | ((unsigned)f2bf(a.w) << 16);
  unsigned w2 = f2bf(b.x) | ((unsigned)f2bf(b.y) << 16);
  unsigned w3 = f2bf(b.z) | ((unsigned)f2bf(b.w) << 16);
  ((uint4*)xb)[idx] = make_uint4(w0, w1, w2, w3);
}

__global__ void transpose_w1_k(const float* __restrict__ src0, unsigned short* __restrict__ dst0) {
  __shared__ float t[32][33];
  const int c = blockIdx.z;
  const int k0 = blockIdx.x << 5, n0 = blockIdx.y << 5;
  const int tx = threadIdx.x, ty = threadIdx.y;
  const float* src = src0 + ((size_t)c << 20);
#pragma unroll
  for (int r = 0; r < 4; ++r)
    t[ty + (r << 3)][tx] = src[((size_t)(k0 + ty + (r << 3)) << 10) + n0 + tx];
  __syncthreads();
  unsigned short* dst = dst0 + ((size_t)c << 20);
#pragma unroll
  for (int r = 0; r < 4; ++r)
    dst[((size_t)(n0 + ty + (r << 3)) << 10) + k0 + tx] = f2bf(t[tx][ty + (r << 3)]);
}

__global__ void transpose_wl_k(const float* __restrict__ Wl, unsigned short* __restrict__ WlT) {
  __shared__ float t[32][33];
  const int c = blockIdx.z;
  const int k0 = blockIdx.x << 5, n0 = blockIdx.y << 5;
  const int tx = threadIdx.x, ty = threadIdx.y;
  const float* src = Wl + (size_t)c * 1025 * 1025;
#pragma unroll
  for (int r = 0; r < 4; ++r) {
    int k = k0 + ty + (r << 3);
    int n = n0 + tx;
    t[ty + (r << 3)][tx] = (n < 1025) ? src[(size_t)k * 1025 + n] : 0.f;
  }
  __syncthreads();
  unsigned short* dst = WlT + (size_t)c * NP * 1024;
#pragma unroll
  for (int r = 0; r < 4; ++r)
    dst[(size_t)(n0 + ty + (r << 3)) * 1024 + k0 + tx] = f2bf(t[tx][ty + (r << 3)]);
}

__global__ __launch_bounds__(256) void wlast_blp_k(const float* __restrict__ Wl,
                                                   const float* __restrict__ bl,
                                                   float* __restrict__ wlastf,
                                                   float* __restrict__ blpf) {
  int idx = blockIdx.x * 256 + threadIdx.x;  // C*NP = 73728
  int c = idx / NP, n = idx - c * NP;
  wlastf[idx] = (n < 1025) ? Wl[((size_t)c * 1025 + 1024) * 1025 + n] : 0.f;
  blpf[idx]   = (n < 1025) ? bl[(size_t)c * 1025 + n] : 0.f;
}

__global__ __launch_bounds__(256) void convert_whead_k(const float* __restrict__ Wmu,
                                                       const float* __restrict__ Wlv,
                                                       unsigned short* __restrict__ WheadT) {
  int idx = blockIdx.x * 256 + threadIdx.x;  // 256*NP
  int rr = idx / NP, k = idx - rr * NP;
  float v = 0.f;
  if (k < 1025) v = (rr < 128) ? Wmu[(size_t)k * 128 + rr] : Wlv[(size_t)k * 128 + (rr - 128)];
  WheadT[idx] = f2bf(v);
}

// ---------------- scorer (unchanged) ----------------

__global__ __launch_bounds__(256) void scorer_k(const unsigned short* __restrict__ h,
                                                const float* __restrict__ w2,
                                                const float* __restrict__ b2,
                                                float* __restrict__ pred_out,
                                                float* __restrict__ cpf) {
  int wv = (blockIdx.x << 2) + (threadIdx.x >> 6);
  int lane = threadIdx.x & 63;
  int c = wv >> 11, b = wv & 2047;
  const unsigned short* hr = h + ((size_t)wv << 10);
  const float* wr = w2 + (c << 10);
  float s = 0.f;
#pragma unroll
  for (int ch = 0; ch < 2; ++ch) {
    int base = ch * 512 + lane * 8;
    s16x8 hv = *(const s16x8*)(hr + base);
    float4 w0 = *(const float4*)(wr + base);
    float4 w1 = *(const float4*)(wr + base + 4);
    s += bf2f((unsigned short)hv[0]) * w0.x + bf2f((unsigned short)hv[1]) * w0.y +
         bf2f((unsigned short)hv[2]) * w0.z + bf2f((unsigned short)hv[3]) * w0.w +
         bf2f((unsigned short)hv[4]) * w1.x + bf2f((unsigned short)hv[5]) * w1.y +
         bf2f((unsigned short)hv[6]) * w1.z + bf2f((unsigned short)hv[7]) * w1.w;
  }
#pragma unroll
  for (int off = 32; off; off >>= 1) s += __shfl_xor(s, off);
  if (lane == 0) {
    float p = 1.f / (1.f + expf(-(s + b2[c])));
    pred_out[((size_t)b << 6) + c] = p;
    cpf[((size_t)b << 6) + c] = p;
  }
}

// ---------------- 256x256 8-phase MFMA GEMM (T1+T2+T3+T4+T5) ----------------
// A [M,K] bf16 row-major, BT [N,K] bf16 row-major. BK=64, 8 waves (2Mx4N).
// MODE 0: h = relu(acc + b1[c,n])            grid (4,8,64)   K=1024
// MODE 1: emb = relu(acc + cp*wlast + blp)   grid (5,8,64)   K=1024 (n0 clamp->896)
// MODE 2: mu/lv/ce = acc + bias -> d_out     grid (1,512,1)  K=1152

#define BAR() __builtin_amdgcn_s_barrier()
#define LGKM0() do { asm volatile("s_waitcnt lgkmcnt(0)" ::: "memory"); \
                     __builtin_amdgcn_sched_barrier(0); } while (0)
#define VM4() asm volatile("s_waitcnt vmcnt(4)" ::: "memory")

#define STAGEA(h, tt, bidx) do { _Pragma("unroll") for (int q_ = 0; q_ < 2; ++q_) \
  async16(Asrc[q_] + ((size_t)(h) * 128) * K + (size_t)(tt) * 64, \
          &sA[bidx][(h) * 8192 + chnk[q_]]); } while (0)
#define STAGEB(h, tt, bidx) do { _Pragma("unroll") for (int q_ = 0; q_ < 2; ++q_) \
  async16(Bsrc[q_] + ((size_t)(h) * 128) * K + (size_t)(tt) * 64, \
          &sB[bidx][(h) * 8192 + chnk[q_]]); } while (0)

#define LOADA(mh, bidx) do { _Pragma("unroll") for (int i_ = 0; i_ < 4; ++i_) { \
  const int ro_ = ((mh) * 128 + wm64 + i_ * 16 + l15) << 6; \
  a[i_][0] = *(const bf16x8*)&sA[bidx][ro_ + ccx0]; \
  a[i_][1] = *(const bf16x8*)&sA[bidx][ro_ + ccx1]; } } while (0)

#define LOADB(nh, bb, bidx) do { _Pragma("unroll") for (int j_ = 0; j_ < 2; ++j_) { \
  const int ro_ = ((nh) * 128 + wn32 + j_ * 16 + l15) << 6; \
  bb[j_][0] = *(const bf16x8*)&sB[bidx][ro_ + ccx0]; \
  bb[j_][1] = *(const bf16x8*)&sB[bidx][ro_ + ccx1]; } } while (0)

#define MMAQ(mh, nh, bb) do { _Pragma("unroll") for (int i_ = 0; i_ < 4; ++i_) \
  _Pragma("unroll") for (int j_ = 0; j_ < 2; ++j_) { \
    acc[(mh)*4+i_][(nh)*2+j_] = __builtin_amdgcn_mfma_f32_16x16x32_bf16( \
        a[i_][0], bb[j_][0], acc[(mh)*4+i_][(nh)*2+j_], 0, 0, 0); \
    acc[(mh)*4+i_][(nh)*2+j_] = __builtin_amdgcn_mfma_f32_16x16x32_bf16( \
        a[i_][1], bb[j_][1], acc[(mh)*4+i_][(nh)*2+j_], 0, 0, 0); \
  } } while (0)

template <int MODE>
__global__ __launch_bounds__(512, 2) void gemm8p_k(
    const unsigned short* __restrict__ A, const unsigned short* __restrict__ BT, const int K,
    const float* __restrict__ e0, const float* __restrict__ e1, const float* __restrict__ e2,
    unsigned short* __restrict__ obf, float* __restrict__ ofl) {
  __shared__ unsigned short sA[2][16384];
  __shared__ unsigned short sB[2][16384];

  constexpr int GX = (MODE == 2) ? 1 : (MODE == 1) ? 5 : 4;
  constexpr int GY = (MODE == 2) ? 512 : 8;
  constexpr int NWG = GX * GY * ((MODE == 2) ? 1 : 64);

  const int tid = threadIdx.x;
  const int lane = tid & 63;
  const int wid = tid >> 6;
  const int wm = wid >> 2, wn = wid & 3;
  const int l15 = lane & 15, l4 = lane >> 4;
  const int wm64 = wm << 6, wn32 = wn << 5;

  // T1: bijective XCD swizzle (NWG % 8 == 0 for all modes)
  const int rbid = blockIdx.x + GX * (blockIdx.y + GY * blockIdx.z);
  const int bid = (rbid & 7) * (NWG >> 3) + (rbid >> 3);
  const int bx = bid % GX;
  const int by = (bid / GX) % GY;
  const int c = bid / (GX * GY);

  int n0 = bx << 8;
  if constexpr (MODE == 1) { if (n0 > NP - 256) n0 = NP - 256; }
  const int m0 = by << 8;

  const unsigned short* Ab = A;
  const unsigned short* Bb;
  if constexpr (MODE == 0)      Bb = BT + ((size_t)c << 20);
  else if constexpr (MODE == 1) Bb = BT + (size_t)c * (NP * 1024);
  else                          Bb = BT;

  // staging geometry: slot s holds source 16B-chunk (row=s>>3, cc=(s&7)^(row&7))
  int rloc[2], csrc[2], chnk[2];
  const unsigned short* Asrc[2];
  const unsigned short* Bsrc[2];
#pragma unroll
  for (int q = 0; q < 2; ++q) {
    const int s = ((wid << 1) + q) * 64 + lane;
    rloc[q] = s >> 3;
    csrc[q] = ((s & 7) ^ ((s >> 3) & 7)) << 3;
    chnk[q] = ((wid << 1) + q) << 9;  // *512 ushorts (=1KB)
    Asrc[q] = Ab + (size_t)(m0 + rloc[q]) * K + csrc[q];
    Bsrc[q] = Bb + (size_t)(n0 + rloc[q]) * K + csrc[q];
  }

  // swizzled ds_read col-chunk offsets (in ushorts)
  const int xorv = l15 & 7;
  const int ccx0 = (l4 ^ xorv) << 3;
  const int ccx1 = ((4 + l4) ^ xorv) << 3;

  f32x4 acc[8][4];
#pragma unroll
  for (int i = 0; i < 8; ++i)
#pragma unroll
    for (int j = 0; j < 4; ++j) acc[i][j] = (f32x4)(0.f);

  bf16x8 a[4][2], b0[2][2], b1[2][2];

  const int nt = K >> 6;

  // prologue: stage tile 0 (order A0,B0,B1,A1), drain, barrier
  STAGEA(0, 0, 0); STAGEB(0, 0, 0); STAGEB(1, 0, 0); STAGEA(1, 0, 0);
  asm volatile("s_waitcnt vmcnt(0)" ::: "memory");
  BAR();

  for (int t = 0; t < nt; ++t) {
    const int cb = t & 1, nb = cb ^ 1;
    const bool pf = (t + 1 < nt);
    // ---- P0: read A-h0 + B-h0, stage A-h0(t+1), MFMA Q(0,0) ----
    LOADA(0, cb);
    LOADB(0, b0, cb);
    if (pf) STAGEA(0, t + 1, nb);
    BAR();
    LGKM0();
    __builtin_amdgcn_s_setprio(1);
    MMAQ(0, 0, b0);
    __builtin_amdgcn_s_setprio(0);
    VM4();   // ensures B-h1(t) landed (for P1 read)
    BAR();
    // ---- P1: read B-h1, stage B-h0(t+1), MFMA Q(0,1) ----
    LOADB(1, b1, cb);
    if (pf) STAGEB(0, t + 1, nb);
    BAR();
    LGKM0();
    __builtin_amdgcn_s_setprio(1);
    MMAQ(0, 1, b1);
    __builtin_amdgcn_s_setprio(0);
    VM4();   // ensures A-h1(t) landed (for P2 read)
    BAR();
    // ---- P2: read A-h1, stage B-h1(t+1), MFMA Q(1,1) ----
    LOADA(1, cb);
    if (pf) STAGEB(1, t + 1, nb);
    BAR();
    LGKM0();
    __builtin_amdgcn_s_setprio(1);
    MMAQ(1, 1, b1);
    __builtin_amdgcn_s_setprio(0);
    BAR();
    // ---- P3: stage A-h1(t+1), MFMA Q(1,0) ----
    if (pf) STAGEA(1, t + 1, nb);
    BAR();
    __builtin_amdgcn_s_setprio(1);
    MMAQ(1, 0, b0);
    __builtin_amdgcn_s_setprio(0);
    VM4();   // ensures A-h0(t+1)+B-h0(t+1) landed (for P0 read of next tile)
    BAR();
  }

  // ---- epilogue ----
  int coln[2][2];
#pragma unroll
  for (int nh = 0; nh < 2; ++nh)
#pragma unroll
    for (int j = 0; j < 2; ++j) coln[nh][j] = n0 + nh * 128 + wn32 + j * 16 + l15;

  if constexpr (MODE == 0) {
    float bias[2][2];
#pragma unroll
    for (int nh = 0; nh < 2; ++nh)
#pragma unroll
      for (int j = 0; j < 2; ++j) bias[nh][j] = e0[(c << 10) + coln[nh][j]];
#pragma unroll
    for (int mh = 0; mh < 2; ++mh)
#pragma unroll
      for (int i = 0; i < 4; ++i)
#pragma unroll
        for (int rr = 0; rr < 4; ++rr) {
          const int row = m0 + mh * 128 + wm64 + i * 16 + (l4 << 2) + rr;
          unsigned short* orow = obf + ((size_t)((c << 11) + row) << 10);
#pragma unroll
          for (int nh = 0; nh < 2; ++nh)
#pragma unroll
            for (int j = 0; j < 2; ++j) {
              float v = acc[mh * 4 + i][nh * 2 + j][rr] + bias[nh][j];
              orow[coln[nh][j]] = f2bf(fmaxf(v, 0.f));
            }
        }
  } else if constexpr (MODE == 1) {
    float wl4[2][2], bb4[2][2];
#pragma unroll
    for (int nh = 0; nh < 2; ++nh)
#pragma unroll
      for (int j = 0; j < 2; ++j) {
        wl4[nh][j] = e0[c * NP + coln[nh][j]];
        bb4[nh][j] = e1[c * NP + coln[nh][j]];
      }
#pragma unroll
    for (int mh = 0; mh < 2; ++mh)
#pragma unroll
      for (int i = 0; i < 4; ++i)
#pragma unroll
        for (int rr = 0; rr < 4; ++rr) {
          const int row = m0 + mh * 128 + wm64 + i * 16 + (l4 << 2) + rr;  // = b
          const float cp = e2[((size_t)row << 6) + c];
          unsigned short* orow = obf + (size_t)((c << 11) + row) * NP;
#pragma unroll
          for (int nh = 0; nh < 2; ++nh)
#pragma unroll
            for (int j = 0; j < 2; ++j) {
              float v = acc[mh * 4 + i][nh * 2 + j][rr] + cp * wl4[nh][j] + bb4[nh][j];
              orow[coln[nh][j]] = f2bf(fmaxf(v, 0.f));
            }
        }
  } else {
    float bias[2][2];
#pragma unroll
    for (int nh = 0; nh < 2; ++nh)
#pragma unroll
      for (int j = 0; j < 2; ++j)
        bias[nh][j] = (nh == 0) ? e0[coln[0][j]] : e1[coln[1][j] - 128];
#pragma unroll
    for (int mh = 0; mh < 2; ++mh)
#pragma unroll
      for (int i = 0; i < 4; ++i)
#pragma unroll
        for (int rr = 0; rr < 4; ++rr) {
          const int rid = m0 + mh * 128 + wm64 + i * 16 + (l4 << 2) + rr;  // c*B + b
          const int cc = rid >> 11, b = rid & 2047;
          const size_t ib = (((size_t)b << 6) + cc) << 7;
#pragma unroll
          for (int j = 0; j < 2; ++j) {  // nh=0 -> mu & ce
            float v = acc[mh * 4 + i][j][rr] + bias[0][j];
            ofl[OFF_MU + ib + coln[0][j]] = v;
            ofl[OFF_CE + ib + coln[0][j]] = v;
          }
#pragma unroll
          for (int j = 0; j < 2; ++j) {  // nh=1 -> logvar
            float v = acc[mh * 4 + i][2 + j][rr] + bias[1][j];
            ofl[OFF_LV + ib + (coln[1][j] - 128)] = v;
          }
        }
  }
}

// ---------------- launcher ----------------

extern "C" void kernel_launch(void* const* d_in, const int* in_sizes, int n_in,
                              void* d_out, int out_size, void* d_ws, size_t ws_size,
                              hipStream_t stream) {
  const float* x   = (const float*)d_in[0];
  const float* W1  = (const float*)d_in[2];
  const float* b1  = (const float*)d_in[3];
  const float* w2  = (const float*)d_in[4];
  const float* b2  = (const float*)d_in[5];
  const float* Wl  = (const float*)d_in[6];
  const float* bl  = (const float*)d_in[7];
  const float* Wmu = (const float*)d_in[8];
  const float* bmu = (const float*)d_in[9];
  const float* Wlv = (const float*)d_in[10];
  const float* blv = (const float*)d_in[11];
  float* out = (float*)d_out;

  char* ws = (char*)d_ws;
  unsigned short* xb     = (unsigned short*)(ws);                  //   4,194,304
  unsigned short* WT     = (unsigned short*)(ws + 4194304ull);     // 150,994,944 (W1T, later WlT)
  float* wlastf          = (float*)(ws + 155189248ull);            //     294,912
  float* blpf            = (float*)(ws + 155484160ull);            //     294,912
  unsigned short* WheadT = (unsigned short*)(ws + 155779072ull);   //     589,824
  float* cpf             = (float*)(ws + 156368896ull);            //     524,288
  unsigned short* hemb   = (unsigned short*)(ws + 156893184ull);   // 301,989,888 (h, later emb)
  // total: 458,883,072 bytes (identical to round-1 footprint)

  convert_x_k<<<1024, 256, 0, stream>>>(x, xb);
  transpose_w1_k<<<dim3(32, 32, 64), dim3(32, 8), 0, stream>>>(W1, WT);
  gemm8p_k<0><<<dim3(4, 8, 64), 512, 0, stream>>>(xb, WT, 1024, b1, nullptr, nullptr, hemb, nullptr);
  scorer_k<<<32768, 256, 0, stream>>>(hemb, w2, b2, out, cpf);
  transpose_wl_k<<<dim3(32, 36, 64), dim3(32, 8), 0, stream>>>(Wl, WT);
  wlast_blp_k<<<288, 256, 0, stream>>>(Wl, bl, wlastf, blpf);
  convert_whead_k<<<1152, 256, 0, stream>>>(Wmu, Wlv, WheadT);
  gemm8p_k<1><<<dim3(5, 8, 64), 512, 0, stream>>>(xb, WT, 1024, wlastf, blpf, cpf, hemb, nullptr);
  gemm8p_k<2><<<dim3(1, 512, 1), 512, 0, stream>>>(hemb, WheadT, 1152, bmu, blv, nullptr, nullptr, out);
}